// Round 1
// baseline (428.499 us; speedup 1.0000x reference)
//
#include <hip/hip_runtime.h>
#include <hip/hip_bf16.h>
#include <math.h>

typedef __attribute__((ext_vector_type(8))) short short8;
typedef __attribute__((ext_vector_type(4))) float f32x4;

#define B_  4
#define T_  2048
#define DM  1024
#define NH  16
#define DH  64
#define BH  (B_*NH)   // 64
#define M_  (B_*T_)   // 8192

static __device__ __forceinline__ short f2bf(float f) {
  unsigned u = __float_as_uint(f);
  unsigned r = (u + 0x7fff + ((u >> 16) & 1)) >> 16;
  return (short)r;
}

static __device__ __forceinline__ void gload_lds16(const void* g, void* l) {
  __builtin_amdgcn_global_load_lds((const __attribute__((address_space(1))) void*)g,
                                   (__attribute__((address_space(3))) void*)l, 16, 0, 0);
}

// ---------------- fp32 -> bf16 convert (vectorized) ----------------
__global__ void k_cvt(const float4* __restrict__ in, ushort4* __restrict__ out, int n4) {
  int i = blockIdx.x * 256 + threadIdx.x;
  if (i >= n4) return;
  float4 v = in[i];
  ushort4 o;
  o.x = (ushort)f2bf(v.x); o.y = (ushort)f2bf(v.y);
  o.z = (ushort)f2bf(v.z); o.w = (ushort)f2bf(v.w);
  out[i] = o;
}

// ---------------- QKV GEMM: C[m][n] = sum_k A[m][k]*W[n][k] ----------------
// 128x128 tile, BK=32, 4 waves (2x2), each wave 64x64 = 4x4 frags of 16x16.
__global__ __launch_bounds__(256) void k_gemm_qkv(
    const short* __restrict__ A,    // [M_, DM] bf16
    const short* __restrict__ W,    // [3*DM, DM] bf16
    short* __restrict__ Qb, short* __restrict__ Kb, short* __restrict__ Vb) {
  const int tid = threadIdx.x;
  const int w = tid >> 6, l = tid & 63;
  const int wr = w >> 1, wc = w & 1;
  const int fq = l >> 4, fr = l & 15;
  const int m0 = blockIdx.x * 128;
  const int n0 = blockIdx.y * 128;

  __shared__ short sA[128 * 32];
  __shared__ short sB[128 * 32];
  f32x4 acc[4][4] = {};

  for (int k0 = 0; k0 < DM; k0 += 32) {
#pragma unroll
    for (int c = 0; c < 2; ++c) {
      int r = w * 32 + c * 16;
      gload_lds16(&A[(size_t)(m0 + r + (l >> 2)) * DM + k0 + (l & 3) * 8], &sA[r * 32]);
      gload_lds16(&W[(size_t)(n0 + r + (l >> 2)) * DM + k0 + (l & 3) * 8], &sB[r * 32]);
    }
    __syncthreads();
    short8 aF[4], bF[4];
#pragma unroll
    for (int m = 0; m < 4; ++m)
      aF[m] = *(const short8*)&sA[(wr * 64 + m * 16 + fr) * 32 + fq * 8];
#pragma unroll
    for (int n = 0; n < 4; ++n)
      bF[n] = *(const short8*)&sB[(wc * 64 + n * 16 + fr) * 32 + fq * 8];
#pragma unroll
    for (int m = 0; m < 4; ++m)
#pragma unroll
      for (int n = 0; n < 4; ++n)
        acc[m][n] = __builtin_amdgcn_mfma_f32_16x16x32_bf16(aF[m], bF[n], acc[m][n], 0, 0, 0);
    __syncthreads();
  }

  // epilogue: scatter into Q/K/V [B][H][T][DH] bf16
#pragma unroll
  for (int m = 0; m < 4; ++m) {
    int row0 = m0 + wr * 64 + m * 16 + fq * 4;
#pragma unroll
    for (int n = 0; n < 4; ++n) {
      int col = n0 + wc * 64 + n * 16 + fr;
      int part = col >> 10, cc = col & 1023;
      int h = cc >> 6, dh = cc & 63;
      short* dst = (part == 0) ? Qb : ((part == 1) ? Kb : Vb);
#pragma unroll
      for (int j = 0; j < 4; ++j) {
        int r = row0 + j;
        int b = r >> 11, t = r & 2047;
        dst[(((size_t)(b * NH + h) * T_ + t)) * DH + dh] = f2bf(acc[m][n][j]);
      }
    }
  }
}

// ---------------- proj GEMM: out[m][n] = sum_k O[m][k]*Wp[n][k] (fp32 out) ----------------
__global__ __launch_bounds__(256) void k_gemm_proj(
    const short* __restrict__ A,    // [M_, DM] bf16 (attention out)
    const short* __restrict__ W,    // [DM, DM] bf16
    float* __restrict__ C) {
  const int tid = threadIdx.x;
  const int w = tid >> 6, l = tid & 63;
  const int wr = w >> 1, wc = w & 1;
  const int fq = l >> 4, fr = l & 15;
  const int m0 = blockIdx.x * 128;
  const int n0 = blockIdx.y * 128;

  __shared__ short sA[128 * 32];
  __shared__ short sB[128 * 32];
  f32x4 acc[4][4] = {};

  for (int k0 = 0; k0 < DM; k0 += 32) {
#pragma unroll
    for (int c = 0; c < 2; ++c) {
      int r = w * 32 + c * 16;
      gload_lds16(&A[(size_t)(m0 + r + (l >> 2)) * DM + k0 + (l & 3) * 8], &sA[r * 32]);
      gload_lds16(&W[(size_t)(n0 + r + (l >> 2)) * DM + k0 + (l & 3) * 8], &sB[r * 32]);
    }
    __syncthreads();
    short8 aF[4], bF[4];
#pragma unroll
    for (int m = 0; m < 4; ++m)
      aF[m] = *(const short8*)&sA[(wr * 64 + m * 16 + fr) * 32 + fq * 8];
#pragma unroll
    for (int n = 0; n < 4; ++n)
      bF[n] = *(const short8*)&sB[(wc * 64 + n * 16 + fr) * 32 + fq * 8];
#pragma unroll
    for (int m = 0; m < 4; ++m)
#pragma unroll
      for (int n = 0; n < 4; ++n)
        acc[m][n] = __builtin_amdgcn_mfma_f32_16x16x32_bf16(aF[m], bF[n], acc[m][n], 0, 0, 0);
    __syncthreads();
  }

#pragma unroll
  for (int m = 0; m < 4; ++m) {
    int row0 = m0 + wr * 64 + m * 16 + fq * 4;
#pragma unroll
    for (int n = 0; n < 4; ++n) {
      int col = n0 + wc * 64 + n * 16 + fr;
#pragma unroll
      for (int j = 0; j < 4; ++j)
        C[(size_t)(row0 + j) * DM + col] = acc[m][n][j];
    }
  }
}

// ---------------- flash attention (causal) ----------------
// Block: (qt, bh). 4 waves x 16 q-rows = 64 q rows. K-tiles of 64.
__global__ __launch_bounds__(256) void k_attn(
    const short* __restrict__ Qb, const short* __restrict__ Kb,
    const short* __restrict__ Vb, short* __restrict__ Ob) {
  const int tid = threadIdx.x;
  const int w = tid >> 6, l = tid & 63;
  const int fq = l >> 4, fr = l & 15;
  const int qt = blockIdx.x, bh = blockIdx.y;
  const int qb = qt * 64 + w * 16;  // wave's first q row

  __shared__ short sK[64 * 64];     // [k][d], XOR-swizzled segs
  __shared__ short sV[64 * 64];     // [d][k] (transposed), XOR-swizzled segs
  __shared__ short sP[4][16 * 64];  // per-wave P, XOR-swizzled

  // Q fragments (held for whole kernel): lane holds Q[qb+fr][kk*32+fq*8 ..+8]
  short8 qa[2];
  {
    const short* Qrow = Qb + ((size_t)bh * T_ + qb + fr) * DH;
#pragma unroll
    for (int kk = 0; kk < 2; ++kk)
      qa[kk] = *(const short8*)&Qrow[kk * 32 + fq * 8];
  }

  float mrun[4] = {-1e30f, -1e30f, -1e30f, -1e30f};
  float lrun[4] = {0.f, 0.f, 0.f, 0.f};
  f32x4 o[4] = {};

  const int nkt = qt + 1;
  for (int kt = 0; kt < nkt; ++kt) {
    // ---- stage K (swizzled rows) and V^T (transpose + swizzle) ----
#pragma unroll
    for (int c = 0; c < 2; ++c) {
      int lin = c * 256 + tid;
      int row = lin >> 3, seg = lin & 7;  // row: k index 0..63, seg: 8-elem chunk of d
      const size_t gbase = ((size_t)bh * T_ + kt * 64 + row) * DH + seg * 8;
      short8 kv = *(const short8*)&Kb[gbase];
      *(short8*)&sK[row * 64 + ((seg ^ (row & 7)) * 8)] = kv;
      short8 vv = *(const short8*)&Vb[gbase];
#pragma unroll
      for (int i = 0; i < 8; ++i) {
        int d = seg * 8 + i;
        sV[d * 64 + (row ^ ((d & 7) << 3))] = vv[i];
      }
    }
    __syncthreads();

    // ---- S = Q K^T (scaled) ----
    f32x4 s[4];
#pragma unroll
    for (int n = 0; n < 4; ++n) {
      f32x4 z = {0.f, 0.f, 0.f, 0.f};
#pragma unroll
      for (int kk = 0; kk < 2; ++kk) {
        int krow = n * 16 + fr;
        short8 kb = *(const short8*)&sK[krow * 64 + (((kk * 4 + fq) ^ (krow & 7)) * 8)];
        z = __builtin_amdgcn_mfma_f32_16x16x32_bf16(qa[kk], kb, z, 0, 0, 0);
      }
      s[n] = z;
    }
#pragma unroll
    for (int n = 0; n < 4; ++n)
#pragma unroll
      for (int j = 0; j < 4; ++j) s[n][j] *= 0.125f;

    // ---- causal mask (only diagonal tile has masked elements) ----
    if (kt == qt) {
#pragma unroll
      for (int n = 0; n < 4; ++n) {
        int kg = kt * 64 + n * 16 + fr;
#pragma unroll
        for (int j = 0; j < 4; ++j) {
          int qg = qb + fq * 4 + j;
          if (kg > qg) s[n][j] = -1e30f;
        }
      }
    }

    // ---- online softmax (per q-row j; row lives in 16 lanes of quad fq) ----
    float alpha[4];
#pragma unroll
    for (int j = 0; j < 4; ++j) {
      float pm = fmaxf(fmaxf(s[0][j], s[1][j]), fmaxf(s[2][j], s[3][j]));
#pragma unroll
      for (int off = 8; off; off >>= 1) pm = fmaxf(pm, __shfl_xor(pm, off));
      float nm = fmaxf(mrun[j], pm);
      alpha[j] = __expf(mrun[j] - nm);
      mrun[j] = nm;
      float rs = 0.f;
#pragma unroll
      for (int n = 0; n < 4; ++n) {
        float p = __expf(s[n][j] - nm);
        s[n][j] = p;
        rs += p;
      }
#pragma unroll
      for (int off = 8; off; off >>= 1) rs += __shfl_xor(rs, off);
      lrun[j] = lrun[j] * alpha[j] + rs;
    }
#pragma unroll
    for (int n = 0; n < 4; ++n)
#pragma unroll
      for (int j = 0; j < 4; ++j) o[n][j] *= alpha[j];

    // ---- P -> LDS (bf16, swizzled), wave-private ----
#pragma unroll
    for (int n = 0; n < 4; ++n)
#pragma unroll
      for (int j = 0; j < 4; ++j) {
        int r = fq * 4 + j;
        int ccol = n * 16 + fr;
        int seg = ccol >> 3, ii = ccol & 7;
        sP[w][r * 64 + ((seg ^ (r & 7)) * 8) + ii] = f2bf(s[n][j]);
      }

    // ---- O += P V ----
#pragma unroll
    for (int kk = 0; kk < 2; ++kk) {
      short8 pa = *(const short8*)&sP[w][fr * 64 + (((kk * 4 + fq) ^ (fr & 7)) * 8)];
#pragma unroll
      for (int n = 0; n < 4; ++n) {
        int d = n * 16 + fr;
        short8 vb = *(const short8*)&sV[d * 64 + (((kk * 4 + fq) ^ (d & 7)) * 8)];
        o[n] = __builtin_amdgcn_mfma_f32_16x16x32_bf16(pa, vb, o[n], 0, 0, 0);
      }
    }
    __syncthreads();  // protect sK/sV before next stage
  }

  // ---- epilogue: O[b][t][h*64+d] bf16 ----
  const int b = bh >> 4, h = bh & 15;
#pragma unroll
  for (int j = 0; j < 4; ++j) {
    float inv = 1.f / lrun[j];
    int qg = qb + fq * 4 + j;
#pragma unroll
    for (int n = 0; n < 4; ++n) {
      int d = n * 16 + fr;
      Ob[((size_t)(b * T_ + qg)) * DM + h * DH + d] = f2bf(o[n][j] * inv);
    }
  }
}

extern "C" void kernel_launch(void* const* d_in, const int* in_sizes, int n_in,
                              void* d_out, int out_size, void* d_ws, size_t ws_size,
                              hipStream_t stream) {
  const float* x     = (const float*)d_in[0];   // [4,2048,1024]
  const float* Wqkv  = (const float*)d_in[1];   // [3072,1024]
  const float* Wproj = (const float*)d_in[2];   // [1024,1024]
  float* out = (float*)d_out;

  short* ws = (short*)d_ws;
  short* xbf   = ws;                                  // 8192*1024
  short* wqkvb = xbf + (size_t)M_ * DM;               // 3072*1024
  short* wprjb = wqkvb + (size_t)3 * DM * DM;         // 1024*1024
  short* Qb    = wprjb + (size_t)DM * DM;             // 64*2048*64
  short* Kb    = Qb + (size_t)BH * T_ * DH;
  short* Vb    = Kb + (size_t)BH * T_ * DH;
  short* Ob    = Vb + (size_t)BH * T_ * DH;           // 8192*1024
  // total: 92.3 MB of d_ws

  k_cvt<<<(M_ * DM / 4) / 256, 256, 0, stream>>>((const float4*)x, (ushort4*)xbf, M_ * DM / 4);
  k_cvt<<<(3 * DM * DM / 4) / 256, 256, 0, stream>>>((const float4*)Wqkv, (ushort4*)wqkvb, 3 * DM * DM / 4);
  k_cvt<<<(DM * DM / 4) / 256, 256, 0, stream>>>((const float4*)Wproj, (ushort4*)wprjb, DM * DM / 4);

  k_gemm_qkv<<<dim3(M_ / 128, 3 * DM / 128), 256, 0, stream>>>(xbf, wqkvb, Qb, Kb, Vb);
  k_attn<<<dim3(T_ / 64, BH), 256, 0, stream>>>(Qb, Kb, Vb, Ob);
  k_gemm_proj<<<dim3(M_ / 128, DM / 128), 256, 0, stream>>>(Ob, wprjb, out);
}

// Round 2
// 205.632 us; speedup vs baseline: 2.0838x; 2.0838x over previous
//
#include <hip/hip_runtime.h>
#include <hip/hip_bf16.h>
#include <math.h>

typedef __attribute__((ext_vector_type(8))) short short8;
typedef __attribute__((ext_vector_type(4))) float f32x4;
typedef __attribute__((ext_vector_type(16))) float f32x16;
typedef __attribute__((ext_vector_type(2))) unsigned uint2v;
typedef __attribute__((ext_vector_type(4))) unsigned uint4v;

#define B_  4
#define T_  2048
#define DM  1024
#define NH  16
#define DH  64
#define BH  (B_*NH)   // 64
#define M_  (B_*T_)   // 8192

static __device__ __forceinline__ short f2bf(float f) {
  unsigned u = __float_as_uint(f);
  unsigned r = (u + 0x7fff + ((u >> 16) & 1)) >> 16;
  return (short)r;
}

static __device__ __forceinline__ unsigned cvtpk(float lo, float hi) {
  unsigned r;
  asm("v_cvt_pk_bf16_f32 %0, %1, %2" : "=v"(r) : "v"(lo), "v"(hi));
  return r;
}

static __device__ __forceinline__ void gload_lds16(const void* g, void* l) {
  __builtin_amdgcn_global_load_lds((const __attribute__((address_space(1))) void*)g,
                                   (__attribute__((address_space(3))) void*)l, 16, 0, 0);
}

// ---------------- fp32 -> bf16 convert (vectorized) ----------------
__global__ void k_cvt(const float4* __restrict__ in, ushort4* __restrict__ out, int n4) {
  int i = blockIdx.x * 256 + threadIdx.x;
  if (i >= n4) return;
  float4 v = in[i];
  ushort4 o;
  o.x = (ushort)f2bf(v.x); o.y = (ushort)f2bf(v.y);
  o.z = (ushort)f2bf(v.z); o.w = (ushort)f2bf(v.w);
  out[i] = o;
}

// ---------------- QKV GEMM: C[m][n] = sum_k A[m][k]*W[n][k] ----------------
// Q,K written [bh][t][dh]; V written TRANSPOSED [bh][dh][t] for attention.
__global__ __launch_bounds__(256) void k_gemm_qkv(
    const short* __restrict__ A,    // [M_, DM] bf16
    const short* __restrict__ W,    // [3*DM, DM] bf16
    short* __restrict__ Qb, short* __restrict__ Kb, short* __restrict__ Vtb) {
  const int tid = threadIdx.x;
  const int w = tid >> 6, l = tid & 63;
  const int wr = w >> 1, wc = w & 1;
  const int fq = l >> 4, fr = l & 15;
  const int m0 = blockIdx.x * 128;
  const int n0 = blockIdx.y * 128;

  __shared__ short sA[128 * 32];
  __shared__ short sB[128 * 32];
  f32x4 acc[4][4] = {};

  for (int k0 = 0; k0 < DM; k0 += 32) {
#pragma unroll
    for (int c = 0; c < 2; ++c) {
      int r = w * 32 + c * 16;
      gload_lds16(&A[(size_t)(m0 + r + (l >> 2)) * DM + k0 + (l & 3) * 8], &sA[r * 32]);
      gload_lds16(&W[(size_t)(n0 + r + (l >> 2)) * DM + k0 + (l & 3) * 8], &sB[r * 32]);
    }
    __syncthreads();
    short8 aF[4], bF[4];
#pragma unroll
    for (int m = 0; m < 4; ++m)
      aF[m] = *(const short8*)&sA[(wr * 64 + m * 16 + fr) * 32 + fq * 8];
#pragma unroll
    for (int n = 0; n < 4; ++n)
      bF[n] = *(const short8*)&sB[(wc * 64 + n * 16 + fr) * 32 + fq * 8];
#pragma unroll
    for (int m = 0; m < 4; ++m)
#pragma unroll
      for (int n = 0; n < 4; ++n)
        acc[m][n] = __builtin_amdgcn_mfma_f32_16x16x32_bf16(aF[m], bF[n], acc[m][n], 0, 0, 0);
    __syncthreads();
  }

#pragma unroll
  for (int m = 0; m < 4; ++m) {
    int row0 = m0 + wr * 64 + m * 16 + fq * 4;
#pragma unroll
    for (int n = 0; n < 4; ++n) {
      int col = n0 + wc * 64 + n * 16 + fr;
      int part = col >> 10, cc = col & 1023;
      int h = cc >> 6, dh = cc & 63;
#pragma unroll
      for (int j = 0; j < 4; ++j) {
        int r = row0 + j;
        int b = r >> 11, t = r & 2047;
        short v = f2bf(acc[m][n][j]);
        if (part == 0)      Qb[(((size_t)(b * NH + h) * T_ + t)) * DH + dh] = v;
        else if (part == 1) Kb[(((size_t)(b * NH + h) * T_ + t)) * DH + dh] = v;
        else                Vtb[(((size_t)(b * NH + h) * DH + dh)) * T_ + t] = v;
      }
    }
  }
}

// ---------------- proj GEMM: out[m][n] = sum_k O[m][k]*Wp[n][k] (fp32 out) ----------------
__global__ __launch_bounds__(256) void k_gemm_proj(
    const short* __restrict__ A,    // [M_, DM] bf16 (attention out)
    const short* __restrict__ W,    // [DM, DM] bf16
    float* __restrict__ C) {
  const int tid = threadIdx.x;
  const int w = tid >> 6, l = tid & 63;
  const int wr = w >> 1, wc = w & 1;
  const int fq = l >> 4, fr = l & 15;
  const int m0 = blockIdx.x * 128;
  const int n0 = blockIdx.y * 128;

  __shared__ short sA[128 * 32];
  __shared__ short sB[128 * 32];
  f32x4 acc[4][4] = {};

  for (int k0 = 0; k0 < DM; k0 += 32) {
#pragma unroll
    for (int c = 0; c < 2; ++c) {
      int r = w * 32 + c * 16;
      gload_lds16(&A[(size_t)(m0 + r + (l >> 2)) * DM + k0 + (l & 3) * 8], &sA[r * 32]);
      gload_lds16(&W[(size_t)(n0 + r + (l >> 2)) * DM + k0 + (l & 3) * 8], &sB[r * 32]);
    }
    __syncthreads();
    short8 aF[4], bF[4];
#pragma unroll
    for (int m = 0; m < 4; ++m)
      aF[m] = *(const short8*)&sA[(wr * 64 + m * 16 + fr) * 32 + fq * 8];
#pragma unroll
    for (int n = 0; n < 4; ++n)
      bF[n] = *(const short8*)&sB[(wc * 64 + n * 16 + fr) * 32 + fq * 8];
#pragma unroll
    for (int m = 0; m < 4; ++m)
#pragma unroll
      for (int n = 0; n < 4; ++n)
        acc[m][n] = __builtin_amdgcn_mfma_f32_16x16x32_bf16(aF[m], bF[n], acc[m][n], 0, 0, 0);
    __syncthreads();
  }

#pragma unroll
  for (int m = 0; m < 4; ++m) {
    int row0 = m0 + wr * 64 + m * 16 + fq * 4;
#pragma unroll
    for (int n = 0; n < 4; ++n) {
      int col = n0 + wc * 64 + n * 16 + fr;
#pragma unroll
      for (int j = 0; j < 4; ++j)
        C[(size_t)(row0 + j) * DM + col] = acc[m][n][j];
    }
  }
}

// ---------------- flash attention v2: swapped-operand 32x32 MFMA ----------------
// Block = 128 q rows (4 waves x 32). Grid (8 pairs, 64 bh): q-tile pair (p, 15-p)
// -> constant 36 K-tiles per block. KVBLK=64.
// S^T = K·Q^T  (lane&31 = q, regs = k)  -> in-lane softmax.
// O^T = V^T·P  (lane&31 = q, regs = d)  -> per-lane rescale.
__global__ __launch_bounds__(256, 2) void k_attn2(
    const short* __restrict__ Qb,   // [bh][t][dh]
    const short* __restrict__ Kb,   // [bh][t][dh]
    const short* __restrict__ Vtb,  // [bh][dh][t]
    short* __restrict__ Ob) {       // [b][t][h*64+d] bf16
  const int tid = threadIdx.x;
  const int w = tid >> 6, l = tid & 63;
  const int lq = l & 31, hi = l >> 5;
  const int bh = blockIdx.y, b = bh >> 4, h = bh & 15;
  const int pair = blockIdx.x;
  const float K2 = 0.125f * 1.44269504f;  // 1/sqrt(64) * log2(e)

  __shared__ short lds[9216];       // sK[4096] | sVt[4096]; reused as sO[4][32][72]
  short* sK = lds;
  short* sVt = lds + 4096;

  for (int ph = 0; ph < 2; ++ph) {
    const int qt = ph ? (15 - pair) : pair;
    const int nkt = 2 * qt + 2;
    const int q0 = qt * 128 + w * 32;
    const int qg = q0 + lq;

    short8 qf[4];
#pragma unroll
    for (int c = 0; c < 4; ++c)
      qf[c] = *(const short8*)&Qb[((size_t)bh * T_ + qg) * DH + c * 16 + hi * 8];

    float m = -3.0e38f, lsum = 0.f;
    f32x16 oacc[2] = {};

    for (int kt = 0; kt < nkt; ++kt) {
      __syncthreads();  // prev-tile reads (or epilogue) done before restage
      // stage K [k][d] and V^T [d][k]: linear LDS dest, pre-swizzled global src
#pragma unroll
      for (int i = 0; i < 2; ++i) {
        int lin = i * 256 + tid;
        int row = lin >> 3, pseg = lin & 7;
        int gseg = pseg ^ (row & 7);
        gload_lds16(&Kb[((size_t)bh * T_ + kt * 64 + row) * DH + gseg * 8], &sK[lin * 8]);
      }
#pragma unroll
      for (int i = 0; i < 2; ++i) {
        int lin = i * 256 + tid;
        int row = lin >> 3, pseg = lin & 7;
        int gseg = pseg ^ (row & 7);
        gload_lds16(&Vtb[((size_t)bh * DH + row) * T_ + kt * 64 + gseg * 8], &sVt[lin * 8]);
      }
      __syncthreads();

      // ---- S^T = K · Q^T : lane holds s[k-reg] for q = lq ----
      float s[32];
#pragma unroll
      for (int st = 0; st < 2; ++st) {
        f32x16 acc = {};
#pragma unroll
        for (int c = 0; c < 4; ++c) {
          int krow = st * 32 + lq;
          short8 kf = *(const short8*)&sK[krow * 64 + (((2 * c + hi) ^ (lq & 7)) * 8)];
          acc = __builtin_amdgcn_mfma_f32_32x32x16_bf16(kf, qf[c], acc, 0, 0, 0);
        }
#pragma unroll
        for (int r = 0; r < 16; ++r) s[st * 16 + r] = acc[r];
      }

      // ---- causal mask (only tiles crossing the diagonal) ----
      if (kt * 64 + 63 > q0) {
#pragma unroll
        for (int st = 0; st < 2; ++st)
#pragma unroll
          for (int r = 0; r < 16; ++r) {
            int kg = kt * 64 + st * 32 + (r & 3) + 8 * (r >> 2) + 4 * hi;
            if (kg > qg) s[st * 16 + r] = -1e30f;
          }
      }

      // ---- online softmax (per-lane row; merge halves via shfl_xor 32) ----
      float pm = s[0];
#pragma unroll
      for (int r = 1; r < 32; ++r) pm = fmaxf(pm, s[r]);
      pm = fmaxf(pm, __shfl_xor(pm, 32));
      float nm = fmaxf(m, pm);
      float alpha = exp2f((m - nm) * K2);
      float nmK = nm * K2;
      m = nm;
      float rs = 0.f;
#pragma unroll
      for (int r = 0; r < 32; ++r) {
        float p = exp2f(fmaf(s[r], K2, -nmK));
        s[r] = p;
        rs += p;
      }
      rs += __shfl_xor(rs, 32);
      lsum = lsum * alpha + rs;
#pragma unroll
      for (int dt = 0; dt < 2; ++dt)
#pragma unroll
        for (int r = 0; r < 16; ++r) oacc[dt][r] *= alpha;

      // ---- P (f32, regs) -> bf16 B-fragments via cvt_pk + permlane32_swap ----
      short8 pb[4];
#pragma unroll
      for (int st = 0; st < 2; ++st) {
        unsigned x0 = cvtpk(s[st * 16 + 0], s[st * 16 + 1]);
        unsigned x1 = cvtpk(s[st * 16 + 2], s[st * 16 + 3]);
        unsigned y0 = cvtpk(s[st * 16 + 4], s[st * 16 + 5]);
        unsigned y1 = cvtpk(s[st * 16 + 6], s[st * 16 + 7]);
        uint2v r0 = __builtin_amdgcn_permlane32_swap(x0, y0, false, false);
        uint2v r1 = __builtin_amdgcn_permlane32_swap(x1, y1, false, false);
        unsigned x2 = cvtpk(s[st * 16 + 8], s[st * 16 + 9]);
        unsigned x3 = cvtpk(s[st * 16 + 10], s[st * 16 + 11]);
        unsigned y2 = cvtpk(s[st * 16 + 12], s[st * 16 + 13]);
        unsigned y3 = cvtpk(s[st * 16 + 14], s[st * 16 + 15]);
        uint2v r2 = __builtin_amdgcn_permlane32_swap(x2, y2, false, false);
        uint2v r3 = __builtin_amdgcn_permlane32_swap(x3, y3, false, false);
        uint4v ta, tb;
        ta[0] = r0[0]; ta[1] = r1[0]; ta[2] = r0[1]; ta[3] = r1[1];
        tb[0] = r2[0]; tb[1] = r3[0]; tb[2] = r2[1]; tb[3] = r3[1];
        pb[st * 2 + 0] = __builtin_bit_cast(short8, ta);
        pb[st * 2 + 1] = __builtin_bit_cast(short8, tb);
      }

      // ---- O^T += V^T · P ----
#pragma unroll
      for (int dt = 0; dt < 2; ++dt) {
#pragma unroll
        for (int c = 0; c < 4; ++c) {
          int drow = dt * 32 + lq;
          short8 vf = *(const short8*)&sVt[drow * 64 + (((2 * c + hi) ^ (lq & 7)) * 8)];
          oacc[dt] = __builtin_amdgcn_mfma_f32_32x32x16_bf16(vf, pb[c], oacc[dt], 0, 0, 0);
        }
      }
    }  // kt

    // ---- epilogue: O^T -> LDS transpose -> coalesced bf16 stores ----
    __syncthreads();  // all waves done reading sK/sVt
    short* sO = lds + w * 2304;  // [32][72] padded
    float inv = 1.0f / lsum;
#pragma unroll
    for (int dt = 0; dt < 2; ++dt)
#pragma unroll
      for (int r = 0; r < 16; r += 2) {
        int dl = dt * 32 + (r & 3) + 8 * (r >> 2) + 4 * hi;
        unsigned pk2 = cvtpk(oacc[dt][r] * inv, oacc[dt][r + 1] * inv);
        *(unsigned*)&sO[lq * 72 + dl] = pk2;
      }
    __syncthreads();
    {
      int qr = l >> 1, hf = l & 1;
      const int tg = qt * 128 + w * 32 + qr;
#pragma unroll
      for (int ss = 0; ss < 4; ++ss) {
        short8 v = *(const short8*)&sO[qr * 72 + hf * 32 + ss * 8];
        *(short8*)&Ob[((size_t)(b * T_) + tg) * DM + h * 64 + hf * 32 + ss * 8] = v;
      }
    }
  }  // ph
}

extern "C" void kernel_launch(void* const* d_in, const int* in_sizes, int n_in,
                              void* d_out, int out_size, void* d_ws, size_t ws_size,
                              hipStream_t stream) {
  const float* x     = (const float*)d_in[0];   // [4,2048,1024]
  const float* Wqkv  = (const float*)d_in[1];   // [3072,1024]
  const float* Wproj = (const float*)d_in[2];   // [1024,1024]
  float* out = (float*)d_out;

  short* ws = (short*)d_ws;
  short* xbf   = ws;                                  // 8192*1024
  short* wqkvb = xbf + (size_t)M_ * DM;               // 3072*1024
  short* wprjb = wqkvb + (size_t)3 * DM * DM;         // 1024*1024
  short* Qb    = wprjb + (size_t)DM * DM;             // 64*2048*64
  short* Kb    = Qb + (size_t)BH * T_ * DH;
  short* Vtb   = Kb + (size_t)BH * T_ * DH;           // transposed [bh][dh][t]
  short* Ob    = Vtb + (size_t)BH * T_ * DH;          // 8192*1024

  k_cvt<<<(M_ * DM / 4) / 256, 256, 0, stream>>>((const float4*)x, (ushort4*)xbf, M_ * DM / 4);
  k_cvt<<<(3 * DM * DM / 4) / 256, 256, 0, stream>>>((const float4*)Wqkv, (ushort4*)wqkvb, 3 * DM * DM / 4);
  k_cvt<<<(DM * DM / 4) / 256, 256, 0, stream>>>((const float4*)Wproj, (ushort4*)wprjb, DM * DM / 4);

  k_gemm_qkv<<<dim3(M_ / 128, 3 * DM / 128), 256, 0, stream>>>(xbf, wqkvb, Qb, Kb, Vtb);
  k_attn2<<<dim3(8, BH), 256, 0, stream>>>(Qb, Kb, Vtb, Ob);
  k_gemm_proj<<<dim3(M_ / 128, DM / 128), 256, 0, stream>>>(Ob, wprjb, out);
}